// Round 9
// baseline (418.995 us; speedup 1.0000x reference)
//
#include <hip/hip_runtime.h>
#include <hip/hip_bf16.h>
#include <math.h>

// Problem constants
#define BB 4
#define TT 1024
#define CCH 1024
#define HH 16
#define NNd 64
#define PAD 65      // fp32 LDS row pad (chunk_scan/outgn)
#define RS 72       // bf16 LDS row stride in shorts (144B = 9x16B, frag-aligned)

typedef short bf16x8 __attribute__((ext_vector_type(8)));
typedef float f32x4 __attribute__((ext_vector_type(4)));

__device__ __forceinline__ unsigned short f2bf(float f) {
  __hip_bfloat16 h = __float2bfloat16(f);
  return __builtin_bit_cast(unsigned short, h);
}
__device__ __forceinline__ float bf2f(unsigned short u) {
  unsigned int x = (unsigned int)u << 16;
  return __builtin_bit_cast(float, x);
}
__device__ __forceinline__ float sigmoidf_(float x) { return 1.0f / (1.0f + expf(-x)); }

// async global->LDS, 16B per lane; LDS dest must be wave-uniform base + 16*lane
__device__ __forceinline__ void gl2lds16(const unsigned short* g, unsigned short* l) {
  __builtin_amdgcn_global_load_lds(
      (const __attribute__((address_space(1))) unsigned int*)g,
      (__attribute__((address_space(3))) unsigned int*)l, 16, 0, 0);
}

// ---------------------------------------------------------------------------
// Transpose tile helper
// ---------------------------------------------------------------------------
__device__ __forceinline__ void transpose_tile(
    const float* __restrict__ in, unsigned short* __restrict__ out,
    int R, int Cc, int r0, int c0, unsigned short (*tile)[68], int t)
{
  const int rr = t >> 4;
  const int cc = (t & 15) * 4;
#pragma unroll
  for (int p = 0; p < 4; ++p) {
    int row = p * 16 + rr;
    float4 v = *(const float4*)(in + (size_t)(r0 + row) * Cc + c0 + cc);
    tile[row][cc]     = f2bf(v.x);
    tile[row][cc + 1] = f2bf(v.y);
    tile[row][cc + 2] = f2bf(v.z);
    tile[row][cc + 3] = f2bf(v.w);
  }
  __syncthreads();
#pragma unroll
  for (int p = 0; p < 4; ++p) {
    int row = p * 16 + rr;
    ushort4 o;
    o.x = tile[cc][row];
    o.y = tile[cc + 1][row];
    o.z = tile[cc + 2][row];
    o.w = tile[cc + 3][row];
    *(ushort4*)(out + (size_t)(c0 + row) * R + r0 + cc) = o;
  }
}

// ---------------------------------------------------------------------------
// prep_kernel: mix (blocks 0..4095) + big4 transposes (4096..5119)
//            + lora transposes (5120..5247), one launch.
// ---------------------------------------------------------------------------
__global__ __launch_bounds__(256) void prep_kernel(
    const float* __restrict__ x,
    const float* __restrict__ cr, const float* __restrict__ cw,
    const float* __restrict__ ck, const float* __restrict__ cv,
    const float* __restrict__ ca, const float* __restrict__ cg,
    unsigned short* __restrict__ xr, unsigned short* __restrict__ xw,
    unsigned short* __restrict__ xk, unsigned short* __restrict__ xv,
    unsigned short* __restrict__ xa, unsigned short* __restrict__ xg,
    const float* __restrict__ W0, const float* __restrict__ W1,
    const float* __restrict__ W2, const float* __restrict__ W3,
    unsigned short* __restrict__ T0, unsigned short* __restrict__ T1,
    unsigned short* __restrict__ T2, unsigned short* __restrict__ T3,
    const float* __restrict__ w1, const float* __restrict__ w2,
    const float* __restrict__ a1, const float* __restrict__ a2,
    const float* __restrict__ g1, const float* __restrict__ g2,
    unsigned short* __restrict__ w1T, unsigned short* __restrict__ w2T,
    unsigned short* __restrict__ a1T, unsigned short* __restrict__ a2T,
    unsigned short* __restrict__ g1T, unsigned short* __restrict__ g2T)
{
  __shared__ unsigned short tile[64][68];
  const int blk = blockIdx.x;
  const int tid = threadIdx.x;
  if (blk < 4096) {
    // ---- token-shift mix ----
    const size_t idx = ((size_t)blk * 256 + tid) * 4;
    const int c = (int)(idx & 1023);
    const int t = (int)((idx >> 10) & 1023);
    float4 xc = *(const float4*)(x + idx);
    float4 xp = make_float4(0.f, 0.f, 0.f, 0.f);
    if (t > 0) xp = *(const float4*)(x + idx - 1024);
    float4 dx = make_float4(xp.x - xc.x, xp.y - xc.y, xp.z - xc.z, xp.w - xc.w);
    auto st = [&](unsigned short* dst, const float* coef) {
      float4 w = *(const float4*)(coef + c);
      ushort4 o;
      o.x = f2bf(fmaf(dx.x, w.x, xc.x));
      o.y = f2bf(fmaf(dx.y, w.y, xc.y));
      o.z = f2bf(fmaf(dx.z, w.z, xc.z));
      o.w = f2bf(fmaf(dx.w, w.w, xc.w));
      *(ushort4*)(dst + idx) = o;
    };
    st(xr, cr); st(xw, cw); st(xk, ck); st(xv, cv); st(xa, ca); st(xg, cg);
  } else if (blk < 5120) {
    const int j = blk - 4096;
    const int z = j >> 8, rem = j & 255;
    const int ty = rem >> 4, tx = rem & 15;
    const float* src = (z == 0) ? W0 : (z == 1) ? W1 : (z == 2) ? W2 : W3;
    unsigned short* dst = (z == 0) ? T0 : (z == 1) ? T1 : (z == 2) ? T2 : T3;
    transpose_tile(src, dst, 1024, 1024, tx * 64, ty * 64, tile, tid);
  } else {
    const int i = blk - 5120;
    const float* src; unsigned short* dst; int R, C, rt, ct;
    if (i < 16)      { src = w1; dst = w1T; R = 1024; C = 64;   rt = i;      ct = 0; }
    else if (i < 32) { src = w2; dst = w2T; R = 64;   C = 1024; rt = 0;      ct = i - 16; }
    else if (i < 48) { src = a1; dst = a1T; R = 1024; C = 64;   rt = i - 32; ct = 0; }
    else if (i < 64) { src = a2; dst = a2T; R = 64;   C = 1024; rt = 0;      ct = i - 48; }
    else if (i < 96) { int k = i - 64; src = g1; dst = g1T; R = 1024; C = 128; rt = k >> 1; ct = k & 1; }
    else             { int k = i - 96; src = g2; dst = g2T; R = 128; C = 1024; rt = k & 1;  ct = k >> 1; }
    transpose_tile(src, dst, R, C, rt * 64, ct * 64, tile, tid);
  }
}

// ---------------------------------------------------------------------------
// gemm_stage1: blocks 0..767 = r/k/v big GEMMs (z=blk/256), 768..895 = lora1.
// BM=128, BK=32, SK=32, global_load_lds staging.
// ---------------------------------------------------------------------------
__global__ __launch_bounds__(256) void gemm_stage1_kernel(
    const unsigned short* __restrict__ xrB, const unsigned short* __restrict__ xkB,
    const unsigned short* __restrict__ xvB,
    const unsigned short* __restrict__ WrT, const unsigned short* __restrict__ WkT,
    const unsigned short* __restrict__ WvT,
    float* __restrict__ r_btc, float* __restrict__ k_btc, float* __restrict__ v_btc,
    const unsigned short* __restrict__ xwB, const unsigned short* __restrict__ xaB,
    const unsigned short* __restrict__ xgB,
    const unsigned short* __restrict__ w1T, const unsigned short* __restrict__ a1T,
    const unsigned short* __restrict__ g1T,
    unsigned short* __restrict__ hwB, unsigned short* __restrict__ haB,
    unsigned short* __restrict__ hgB)
{
  constexpr int K = 1024, SK = 32;
  __shared__ __align__(16) unsigned short As[128 * SK];
  __shared__ __align__(16) unsigned short Bs[128 * SK];
  const int blk = blockIdx.x;
  const int tid = threadIdx.x;
  const int wv = tid >> 6, lane = tid & 63;
  const int fr = lane & 15, q = lane >> 4;
  const int arow = tid >> 2;
  const int akc = (tid & 3) * 8;

  if (blk < 768) {
    // ---- big3 GEMM: z selects r/k/v ----
    const int z = blk >> 8, rem = blk & 255;
    const int m0 = (rem & 31) * 128;
    const int n0 = (rem >> 5) * 128;
    const unsigned short* A = (z == 0) ? xrB : (z == 1) ? xkB : xvB;
    const unsigned short* BT = (z == 0) ? WrT : (z == 1) ? WkT : WvT;
    float* out = (z == 0) ? r_btc : (z == 1) ? k_btc : v_btc;
    const int wave_m = wv >> 1, wave_n = wv & 1;

    f32x4 acc[4][4];
#pragma unroll
    for (int i = 0; i < 4; i++)
#pragma unroll
      for (int j = 0; j < 4; j++) acc[i][j] = (f32x4){0.f, 0.f, 0.f, 0.f};

    for (int k0 = 0; k0 < K; k0 += 32) {
#pragma unroll
      for (int i = 0; i < 2; ++i)
        gl2lds16(A + (size_t)(m0 + arow + i * 64) * K + k0 + akc, As + i * 2048 + wv * 512);
#pragma unroll
      for (int i = 0; i < 2; ++i)
        gl2lds16(BT + (size_t)(n0 + arow + i * 64) * K + k0 + akc, Bs + i * 2048 + wv * 512);
      __syncthreads();
      bf16x8 af[4], bfv[4];
#pragma unroll
      for (int i = 0; i < 4; i++)
        af[i] = *(const bf16x8*)(&As[(wave_m * 64 + i * 16 + fr) * SK + q * 8]);
#pragma unroll
      for (int j = 0; j < 4; j++)
        bfv[j] = *(const bf16x8*)(&Bs[(wave_n * 64 + j * 16 + fr) * SK + q * 8]);
#pragma unroll
      for (int i = 0; i < 4; i++)
#pragma unroll
        for (int j = 0; j < 4; j++)
          acc[i][j] = __builtin_amdgcn_mfma_f32_16x16x32_bf16(af[i], bfv[j], acc[i][j], 0, 0, 0);
      __syncthreads();
    }
#pragma unroll
    for (int i = 0; i < 4; i++)
#pragma unroll
      for (int j = 0; j < 4; j++) {
        const int mb = m0 + wave_m * 64 + i * 16 + q * 4;
        const int n = n0 + wave_n * 64 + j * 16 + fr;
#pragma unroll
        for (int r = 0; r < 4; r++)
          out[(size_t)(mb + r) * 1024 + n] = acc[i][j][r];
      }
  } else {
    // ---- lora1: y=0 hw=tanh, y=1 ha, y=2/3 hg sigmoid halves ----
    const int j2 = blk - 768;
    const int y = j2 >> 5;
    const int m0 = (j2 & 31) * 128;
    const unsigned short* A  = (y == 0) ? xwB : (y == 1) ? xaB : xgB;
    const unsigned short* BT = (y == 0) ? w1T : (y == 1) ? a1T : (g1T + (size_t)(y - 2) * 64 * K);
    unsigned short* outb = (y == 0) ? hwB : (y == 1) ? haB : hgB;
    const int Nout = (y < 2) ? 64 : 128;
    const int ncol0 = (y < 2) ? 0 : (y - 2) * 64;

    f32x4 acc[2][4];
#pragma unroll
    for (int i = 0; i < 2; i++)
#pragma unroll
      for (int j = 0; j < 4; j++) acc[i][j] = (f32x4){0.f, 0.f, 0.f, 0.f};

    for (int k0 = 0; k0 < K; k0 += 32) {
#pragma unroll
      for (int i = 0; i < 2; ++i)
        gl2lds16(A + (size_t)(m0 + arow + i * 64) * K + k0 + akc, As + i * 2048 + wv * 512);
      gl2lds16(BT + (size_t)arow * K + k0 + akc, Bs + wv * 512);
      __syncthreads();
      bf16x8 af[2], bfv[4];
#pragma unroll
      for (int i = 0; i < 2; i++)
        af[i] = *(const bf16x8*)(&As[(wv * 32 + i * 16 + fr) * SK + q * 8]);
#pragma unroll
      for (int j = 0; j < 4; j++)
        bfv[j] = *(const bf16x8*)(&Bs[(j * 16 + fr) * SK + q * 8]);
#pragma unroll
      for (int i = 0; i < 2; i++)
#pragma unroll
        for (int j = 0; j < 4; j++)
          acc[i][j] = __builtin_amdgcn_mfma_f32_16x16x32_bf16(af[i], bfv[j], acc[i][j], 0, 0, 0);
      __syncthreads();
    }
#pragma unroll
    for (int i = 0; i < 2; i++)
#pragma unroll
      for (int j = 0; j < 4; j++) {
        const int mb = m0 + wv * 32 + i * 16 + q * 4;
        const int n = ncol0 + j * 16 + fr;
#pragma unroll
        for (int r = 0; r < 4; r++) {
          float val = acc[i][j][r];
          if (y == 0) val = tanhf(val);
          else if (y >= 2) val = sigmoidf_(val);
          outb[(size_t)(mb + r) * Nout + n] = f2bf(val);
        }
      }
  }
}

// z-batched LoRA-2 GEMMs: z=0 wraw (fp32), z=1 araw (fp32), z=2 g (bf16).
__global__ __launch_bounds__(256) void lora2_kernel(
    const unsigned short* __restrict__ hwB, const unsigned short* __restrict__ haB,
    const unsigned short* __restrict__ hgB,
    const unsigned short* __restrict__ w2T, const unsigned short* __restrict__ a2T,
    const unsigned short* __restrict__ g2T,
    float* __restrict__ wraw, float* __restrict__ araw,
    unsigned short* __restrict__ gfB)
{
  constexpr int N = 1024, SK = 32;
  __shared__ __align__(16) unsigned short As[128 * SK];
  __shared__ __align__(16) unsigned short Bs[128 * SK];
  const int z = blockIdx.z;
  const unsigned short* A = (z == 0) ? hwB : (z == 1) ? haB : hgB;
  const unsigned short* BT = (z == 0) ? w2T : (z == 1) ? a2T : g2T;
  const int K = (z == 2) ? 128 : 64;

  const int tid = threadIdx.x;
  const int wv = tid >> 6, lane = tid & 63;
  const int fr = lane & 15, q = lane >> 4;
  const int wave_m = wv >> 1, wave_n = wv & 1;
  const int m0 = blockIdx.x * 128;
  const int n0 = blockIdx.y * 128;

  f32x4 acc[4][4];
#pragma unroll
  for (int i = 0; i < 4; i++)
#pragma unroll
    for (int j = 0; j < 4; j++) acc[i][j] = (f32x4){0.f, 0.f, 0.f, 0.f};

  const int arow = tid >> 2;
  const int akc = (tid & 3) * 8;

  for (int k0 = 0; k0 < K; k0 += 32) {
#pragma unroll
    for (int i = 0; i < 2; ++i)
      gl2lds16(A + (size_t)(m0 + arow + i * 64) * K + k0 + akc, As + i * 2048 + wv * 512);
#pragma unroll
    for (int i = 0; i < 2; ++i)
      gl2lds16(BT + (size_t)(n0 + arow + i * 64) * K + k0 + akc, Bs + i * 2048 + wv * 512);
    __syncthreads();
    bf16x8 af[4], bfv[4];
#pragma unroll
    for (int i = 0; i < 4; i++)
      af[i] = *(const bf16x8*)(&As[(wave_m * 64 + i * 16 + fr) * SK + q * 8]);
#pragma unroll
    for (int j = 0; j < 4; j++)
      bfv[j] = *(const bf16x8*)(&Bs[(wave_n * 64 + j * 16 + fr) * SK + q * 8]);
#pragma unroll
    for (int i = 0; i < 4; i++)
#pragma unroll
      for (int j = 0; j < 4; j++)
        acc[i][j] = __builtin_amdgcn_mfma_f32_16x16x32_bf16(af[i], bfv[j], acc[i][j], 0, 0, 0);
    __syncthreads();
  }
#pragma unroll
  for (int i = 0; i < 4; i++)
#pragma unroll
    for (int j = 0; j < 4; j++) {
      const int mb = m0 + wave_m * 64 + i * 16 + q * 4;
      const int n = n0 + wave_n * 64 + j * 16 + fr;
#pragma unroll
      for (int r = 0; r < 4; r++) {
        if (z == 0)      wraw[(size_t)(mb + r) * N + n] = acc[i][j][r];
        else if (z == 1) araw[(size_t)(mb + r) * N + n] = acc[i][j][r];
        else             gfB[(size_t)(mb + r) * N + n] = f2bf(acc[i][j][r]);
      }
    }
}

// Final projection GEMM (yg @ WoT -> out fp32)
__global__ __launch_bounds__(256) void gemm_out_kernel(
    const unsigned short* __restrict__ A,
    const unsigned short* __restrict__ BT,
    float* __restrict__ out)
{
  constexpr int K = 1024, N = 1024, SK = 32;
  __shared__ __align__(16) unsigned short As[128 * SK];
  __shared__ __align__(16) unsigned short Bs[128 * SK];
  const int tid = threadIdx.x;
  const int wv = tid >> 6, lane = tid & 63;
  const int fr = lane & 15, q = lane >> 4;
  const int wave_m = wv >> 1, wave_n = wv & 1;
  const int m0 = blockIdx.x * 128;
  const int n0 = blockIdx.y * 128;

  f32x4 acc[4][4];
#pragma unroll
  for (int i = 0; i < 4; i++)
#pragma unroll
    for (int j = 0; j < 4; j++) acc[i][j] = (f32x4){0.f, 0.f, 0.f, 0.f};

  const int arow = tid >> 2;
  const int akc = (tid & 3) * 8;

  for (int k0 = 0; k0 < K; k0 += 32) {
#pragma unroll
    for (int i = 0; i < 2; ++i)
      gl2lds16(A + (size_t)(m0 + arow + i * 64) * K + k0 + akc, As + i * 2048 + wv * 512);
#pragma unroll
    for (int i = 0; i < 2; ++i)
      gl2lds16(BT + (size_t)(n0 + arow + i * 64) * K + k0 + akc, Bs + i * 2048 + wv * 512);
    __syncthreads();
    bf16x8 af[4], bfv[4];
#pragma unroll
    for (int i = 0; i < 4; i++)
      af[i] = *(const bf16x8*)(&As[(wave_m * 64 + i * 16 + fr) * SK + q * 8]);
#pragma unroll
    for (int j = 0; j < 4; j++)
      bfv[j] = *(const bf16x8*)(&Bs[(wave_n * 64 + j * 16 + fr) * SK + q * 8]);
#pragma unroll
    for (int i = 0; i < 4; i++)
#pragma unroll
      for (int j = 0; j < 4; j++)
        acc[i][j] = __builtin_amdgcn_mfma_f32_16x16x32_bf16(af[i], bfv[j], acc[i][j], 0, 0, 0);
    __syncthreads();
  }
#pragma unroll
  for (int i = 0; i < 4; i++)
#pragma unroll
    for (int j = 0; j < 4; j++) {
      const int mb = m0 + wave_m * 64 + i * 16 + q * 4;
      const int n = n0 + wave_n * 64 + j * 16 + fr;
#pragma unroll
      for (int r = 0; r < 4; r++)
        out[(size_t)(mb + r) * N + n] = acc[i][j][r];
    }
}

// ---------------------------------------------------------------------------
// Phase 1 (MFMA): per-(bh,chunk) chunked-DPLR operators, postproc FUSED.
// L matrix (LBA) now fp32 in global scratch LbG (no bf2f in solve, LDS slot
// freed -> 64.2 KB). Pass-2 uses 1 expf + 1 rcp per token (running product).
// ---------------------------------------------------------------------------
__global__ __launch_bounds__(256, 2) void chunk_ops_kernel(
    const float* __restrict__ r_btc, const float* __restrict__ k_btc,
    const float* __restrict__ v_btc, const float* __restrict__ wraw,
    const float* __restrict__ araw,
    const float* __restrict__ w0, const float* __restrict__ a0,
    const float* __restrict__ k_k, const float* __restrict__ k_a,
    const float* __restrict__ r_k,
    unsigned short* __restrict__ McG, unsigned short* __restrict__ NcG,
    unsigned short* __restrict__ PcG, unsigned short* __restrict__ OlG,
    unsigned short* __restrict__ DkG, float* __restrict__ s3G,
    float* __restrict__ LbG)
{
  extern __shared__ char smraw[];
  unsigned short* AHb  = (unsigned short*)smraw;   // S1: Ahat -> XTb
  unsigned short* RHb  = AHb + 64 * RS;            // S2: Rhat (bf16, thru E)
  unsigned short* BPb  = RHb + 64 * RS;            // S3: Bp -> LKA/Y -> QTb
  unsigned short* KPb  = BPb + 64 * RS;            // S4: Kp -> DBR
  unsigned short* BPTb = KPb + 64 * RS;            // S5: Btil^T [i][t]
  unsigned short* KPTb = BPTb + 64 * RS;           // S6: Ktil^T [i][t]
  unsigned short* VSTb = KPTb + 64 * RS;           // S7: V^T [n][t]
  float* GLs = (float*)(VSTb + 64 * RS);           // [64] total log-decay
  float* SS  = GLs + 64;                           // [4][64] strip sums
  unsigned short* XTb = AHb;                       // overlay after solve
  unsigned short* LKb = BPb;                       // overlay after Gram
  unsigned short* QTb = BPb;                       // overlay after Qloc
  unsigned short* DBb = KPb;                       // overlay after Gram

  const int inst = blockIdx.x;
  const int bh = inst >> 4, c = inst & 15;
  const int b = bh >> 4, h = bh & 15;
  const int tid = threadIdx.x;
  const int lane = tid & 63;
  const int wv = tid >> 6;
  const int jl = lane;
  const int ch = h * 64 + jl;
  const size_t base = ((size_t)(b * 1024 + c * 64) * 1024) + ch;

  const float p_w0 = w0[ch], p_a0 = a0[ch];
  const float p_kk = k_k[ch], p_ka = k_a[ch], p_rk = r_k[ch];
  const float EM = 0.60653065971263342f;  // e^{-0.5}

  // ---- pass 1: log-decay for my 16 rows + strip sum ----
  float lwv[16];
  {
    float run = 0.f;
#pragma unroll
    for (int u = 0; u < 16; ++u) {
      const float wr = wraw[base + (size_t)(16 * wv + u) * 1024];
      const float lw = -EM * sigmoidf_(p_w0 + wr);
      lwv[u] = lw; run += lw;
    }
    SS[wv * 64 + jl] = run;
  }
  __syncthreads();
  const float s0 = SS[0 * 64 + jl], s1 = SS[1 * 64 + jl];
  const float s2 = SS[2 * 64 + jl], s3s = SS[3 * 64 + jl];
  const float goff = (wv > 0 ? s0 : 0.f) + (wv > 1 ? s1 : 0.f) + (wv > 2 ? s2 : 0.f);
  const float gl = s0 + s1 + s2 + s3s;
  if (wv == 0) GLs[jl] = gl;

  // ---- pass 2: per-token transforms + factor matrices ----
  {
    float grun = goff;
    float e_prev = expf(goff);          // exp(g_{t-1})
    const float e_gl = expf(gl);
#pragma unroll
    for (int u = 0; u < 16; ++u) {
      const int t = 16 * wv + u;
      const size_t gi = base + (size_t)t * 1024;
      const float kv = k_btc[gi], rv = r_btc[gi], vv = v_btc[gi], ar = araw[gi];
      const float av = sigmoidf_(p_a0 + ar);
      const float kkx = kv * p_kk;
      float ssq = kkx * kkx;
#pragma unroll
      for (int m = 1; m < 64; m <<= 1) ssq += __shfl_xor(ssq, m);
      const float scale = 1.0f / fmaxf(sqrtf(ssq), 1e-12f);
      const float kkn = kkx * scale;
      const float bb = kkn * av;
      const float kmod = kv * (1.0f + (av - 1.0f) * p_ka);
      float s3 = rv * kmod * p_rk;
#pragma unroll
      for (int m = 1; m < 64; m <<= 1) s3 += __shfl_xor(s3, m);
      if (jl == 0) s3G[(bh << 10) + (c << 6) + t] = s3;
      grun += lwv[u];
      const float e_gu = expf(grun);                     // exp(g_u), <= 1
      const float em = __builtin_amdgcn_rcpf(e_gu);      // exp(-g_u)
      const float egl = e_gl * em;                       // exp(gl-g_u) <= 1
      AHb[t * RS + jl] = f2bf(-kkn * e_prev);
      BPb[t * RS + jl] = f2bf(bb * em);
      KPb[t * RS + jl] = f2bf(kmod * em);
      BPTb[jl * RS + t] = f2bf(bb * egl);
      KPTb[jl * RS + t] = f2bf(kmod * egl);
      RHb[t * RS + jl] = f2bf(rv * e_gu);
      VSTb[jl * RS + t] = f2bf(vv);
      e_prev = e_gu;
    }
  }
  __syncthreads();

  const int fr = lane & 15, q = lane >> 4;
  const int i0 = wv * 16;
  float* Lb = LbG + (size_t)inst * 4096;

  // ---- Gram products via MFMA: LBA(->global fp32), LKA, DBR, DKR(->global) ----
  {
    f32x4 aLB[4], aLK[4], aDB[4], aDK[4];
#pragma unroll
    for (int j = 0; j < 4; ++j) {
      aLB[j] = (f32x4){0.f, 0.f, 0.f, 0.f}; aLK[j] = (f32x4){0.f, 0.f, 0.f, 0.f};
      aDB[j] = (f32x4){0.f, 0.f, 0.f, 0.f}; aDK[j] = (f32x4){0.f, 0.f, 0.f, 0.f};
    }
#pragma unroll
    for (int ks = 0; ks < 2; ++ks) {
      const int ko = ks * 32 + q * 8;
      bf16x8 fA = *(const bf16x8*)(AHb + (i0 + fr) * RS + ko);
      bf16x8 fR = *(const bf16x8*)(RHb + (i0 + fr) * RS + ko);
#pragma unroll
      for (int j = 0; j < 4; ++j) {
        bf16x8 fB = *(const bf16x8*)(BPb + (j * 16 + fr) * RS + ko);
        bf16x8 fK = *(const bf16x8*)(KPb + (j * 16 + fr) * RS + ko);
        aLB[j] = __builtin_amdgcn_mfma_f32_16x16x32_bf16(fA, fB, aLB[j], 0, 0, 0);
        aLK[j] = __builtin_amdgcn_mfma_f32_16x16x32_bf16(fA, fK, aLK[j], 0, 0, 0);
        aDB[j] = __builtin_amdgcn_mfma_f32_16x16x32_bf16(fR, fB, aDB[j], 0, 0, 0);
        aDK[j] = __builtin_amdgcn_mfma_f32_16x16x32_bf16(fR, fK, aDK[j], 0, 0, 0);
      }
    }
    __syncthreads();   // all Gram fragment reads done before overlay stores
#pragma unroll
    for (int j = 0; j < 4; ++j) {
      const int s = j * 16 + fr;
#pragma unroll
      for (int r = 0; r < 4; ++r) {
        const int t = i0 + q * 4 + r;
        Lb[t * 64 + s] = (s < t) ? aLB[j][r] : 0.f;
        LKb[t * RS + s] = f2bf((s < t) ? aLK[j][r] : 0.f);
        DBb[t * RS + s] = f2bf((s <= t) ? aDB[j][r] : 0.f);
        DkG[(size_t)inst * 4096 + t * 64 + s] = f2bf((s <= t) ? aDK[j][r] : 0.f);
      }
    }
  }
  __syncthreads();

  // ---- triangular solve (I-LBA)[X|Y] = [Ahat|LKA] (fp32, 128 threads) ----
  // L rows read from global fp32 (L2-hot, wave-uniform broadcasts, no bf2f).
  if (tid < 128) {
    const int jc = lane;
    const bool isX = (wv == 0);
    float x[64];
#pragma unroll
    for (int t = 0; t < 64; ++t)
      x[t] = bf2f(isX ? AHb[t * RS + jc] : LKb[t * RS + jc]);
#pragma unroll
    for (int t = 1; t < 64; ++t) {
      float a0r = 0.f, a1r = 0.f, a2r = 0.f, a3r = 0.f;
      const float* lr = Lb + t * 64;
#pragma unroll
      for (int s = 0; s + 4 <= t; s += 4) {
        float4 l4 = *(const float4*)(lr + s);
        a0r = fmaf(l4.x, x[s], a0r);     a1r = fmaf(l4.y, x[s + 1], a1r);
        a2r = fmaf(l4.z, x[s + 2], a2r); a3r = fmaf(l4.w, x[s + 3], a3r);
      }
#pragma unroll
      for (int s = t & ~3; s < t; ++s) a0r = fmaf(lr[s], x[s], a0r);
      x[t] += (a0r + a1r) + (a2r + a3r);
    }
    if (isX) {
#pragma unroll
      for (int t = 0; t < 64; t += 2) {
        unsigned int pk = (unsigned int)f2bf(x[t]) | ((unsigned int)f2bf(x[t + 1]) << 16);
        *(unsigned int*)(XTb + jc * RS + t) = pk;
      }
    } else {
#pragma unroll
      for (int t = 0; t < 64; ++t) LKb[t * RS + jc] = f2bf(x[t]);
    }
  }
  __syncthreads();

  // ---- prefetch DKR fragments from global (L2-hot: our own writes) ----
  bf16x8 fDK0, fDK1;
  {
    const unsigned short* dkp = DkG + (size_t)inst * 4096 + (i0 + fr) * 64 + q * 8;
    fDK0 = *(const bf16x8*)(dkp);
    fDK1 = *(const bf16x8*)(dkp + 32);
  }

  // ---- Qloc = Y V (MFMA) ----
  {
    f32x4 qa[4];
#pragma unroll
    for (int j = 0; j < 4; ++j) qa[j] = (f32x4){0.f, 0.f, 0.f, 0.f};
#pragma unroll
    for (int ks = 0; ks < 2; ++ks) {
      const int ko = ks * 32 + q * 8;
      bf16x8 fY = *(const bf16x8*)(LKb + (i0 + fr) * RS + ko);
#pragma unroll
      for (int j = 0; j < 4; ++j) {
        bf16x8 fV = *(const bf16x8*)(VSTb + (j * 16 + fr) * RS + ko);
        qa[j] = __builtin_amdgcn_mfma_f32_16x16x32_bf16(fY, fV, qa[j], 0, 0, 0);
      }
    }
    __syncthreads();   // Qloc reads of LKb done -> overlay QTb
#pragma unroll
    for (int j = 0; j < 4; ++j) {
      const int n = j * 16 + fr;
      ushort4 pk;
      pk.x = f2bf(qa[j][0]); pk.y = f2bf(qa[j][1]);
      pk.z = f2bf(qa[j][2]); pk.w = f2bf(qa[j][3]);
      *(ushort4*)(QTb + n * RS + i0 + q * 4) = pk;
    }
  }
  __syncthreads();

  // ---- final operators: Mc, Ncc, Pc, Oloc (MFMA) -> global bf16 ----
  {
    f32x4 mA[4], nA[4], pA[4], oA[4];
#pragma unroll
    for (int j = 0; j < 4; ++j) {
      mA[j] = (f32x4){0.f, 0.f, 0.f, 0.f}; nA[j] = (f32x4){0.f, 0.f, 0.f, 0.f};
      pA[j] = (f32x4){0.f, 0.f, 0.f, 0.f}; oA[j] = (f32x4){0.f, 0.f, 0.f, 0.f};
    }
#pragma unroll
    for (int ks = 0; ks < 2; ++ks) {
      const int ko = ks * 32 + q * 8;
      bf16x8 fBT = *(const bf16x8*)(BPTb + (i0 + fr) * RS + ko);
      bf16x8 fKT = *(const bf16x8*)(KPTb + (i0 + fr) * RS + ko);
      bf16x8 fDB = *(const bf16x8*)(DBb + (i0 + fr) * RS + ko);
      bf16x8 fDK = ks ? fDK1 : fDK0;
#pragma unroll
      for (int j = 0; j < 4; ++j) {
        bf16x8 fXT = *(const bf16x8*)(XTb + (j * 16 + fr) * RS + ko);
        bf16x8 fQT = *(const bf16x8*)(QTb + (j * 16 + fr) * RS + ko);
        bf16x8 fVT = *(const bf16x8*)(VSTb + (j * 16 + fr) * RS + ko);
        mA[j] = __builtin_amdgcn_mfma_f32_16x16x32_bf16(fBT, fXT, mA[j], 0, 0, 0);
        nA[j] = __builtin_amdgcn_mfma_f32_16x16x32_bf16(fBT, fQT, nA[j], 0, 0, 0);
        nA[j] = __builtin_amdgcn_mfma_f32_16x16x32_bf16(fKT, fVT, nA[j], 0, 0, 0);
        pA[j] = __builtin_amdgcn_mfma_f32_16x16x32_bf16(fDB, fXT, pA[j], 0, 0, 0);
        oA[j] = __builtin_amdgcn_mfma_f32_16x16x32_bf16(fDB, fQT, oA[j], 0, 0, 0);
        oA[j] = __builtin_amdgcn_mfma_f32_16x16x32_bf16(fDK, fVT, oA[j], 0, 0, 0);
      }
    }
    const size_t ob = (size_t)inst * 4096;
    float eg[4];
#pragma unroll
    for (int r = 0; r < 4; ++r) eg[r] = expf(GLs[i0 + q * 4 + r]);
#pragma unroll
    for (int j = 0; j < 4; ++j) {
      const int col = j * 16 + fr;
#pragma unroll
      for (int r = 0; r < 4; ++r) {
        const int row = i0 + q * 4 + r;
        const size_t oi = ob + (size_t)row * 64 + col;
        McG[oi] = f2bf(mA[j][r] + (row == col ? eg[r] : 0.f));
        NcG[oi] = f2bf(nA[j][r]);
        PcG[oi] = f2bf(pA[j][r] + bf2f(RHb[row * RS + col]));
        OlG[oi] = f2bf(oA[j][r]);
      }
    }
  }
}

// ---------------------------------------------------------------------------
// Phase 2: sequential chunk-state propagation per (b,h): ST' = Mc ST + Ncc.
// ---------------------------------------------------------------------------
__global__ __launch_bounds__(256) void chunk_scan_kernel(
    const unsigned short* __restrict__ McG, const unsigned short* __restrict__ NcG,
    unsigned short* __restrict__ Sch)
{
  __shared__ float ST[64 * PAD];
  __shared__ float MB[64 * PAD];
  const int bh = blockIdx.x;
  const int tid = threadIdx.x;
  const int it = tid >> 4, jt = tid & 15;

#pragma unroll
  for (int q = 0; q < 16; ++q) {
    int idx = q * 256 + tid;
    ST[(idx >> 6) * PAD + (idx & 63)] = 0.f;
  }
  __syncthreads();

  for (int c = 0; c < 16; ++c) {
    const size_t ob = ((((size_t)bh << 4) + c) << 12);
#pragma unroll
    for (int q = 0; q < 4; ++q) {
      int idx = q * 1024 + tid * 4;
      int row = idx >> 6, col = idx & 63;
      ushort4 sv;
      sv.x = f2bf(ST[row * PAD + col]);     sv.y = f2bf(ST[row * PAD + col + 1]);
      sv.z = f2bf(ST[row * PAD + col + 2]); sv.w = f2bf(ST[row * PAD + col + 3]);
      *(ushort4*)(Sch + ob + idx) = sv;
      ushort4 mv = *(const ushort4*)(McG + ob + idx);
      MB[row * PAD + col] = bf2f(mv.x);     MB[row * PAD + col + 1] = bf2f(mv.y);
      MB[row * PAD + col + 2] = bf2f(mv.z); MB[row * PAD + col + 3] = bf2f(mv.w);
    }
    __syncthreads();
    float acc[4][4];
#pragma unroll
    for (int u = 0; u < 4; ++u) {
      ushort4 n4 = *(const ushort4*)(NcG + ob + (size_t)(4 * it + u) * 64 + 4 * jt);
      acc[u][0] = bf2f(n4.x); acc[u][1] = bf2f(n4.y);
      acc[u][2] = bf2f(n4.z); acc[u][3] = bf2f(n4.w);
    }
#pragma unroll 4
    for (int pp = 0; pp < 64; ++pp) {
      float mv[4], sv[4];
#pragma unroll
      for (int u = 0; u < 4; ++u) mv[u] = MB[(4 * it + u) * PAD + pp];
#pragma unroll
      for (int v = 0; v < 4; ++v) sv[v] = ST[pp * PAD + 4 * jt + v];
#pragma unroll
      for (int u = 0; u < 4; ++u)
#pragma unroll
        for (int v = 0; v < 4; ++v) acc[u][v] = fmaf(mv[u], sv[v], acc[u][v]);
    }
    __syncthreads();
#pragma unroll
    for (int u = 0; u < 4; ++u)
#pragma unroll
      for (int v = 0; v < 4; ++v) ST[(4 * it + u) * PAD + 4 * jt + v] = acc[u][v];
    __syncthreads();
  }
}

// ---------------------------------------------------------------------------
// Phase 3 + GroupNorm fused: Out = Pc ST + Oloc; per-row norm; + s3*v; *g.
// ---------------------------------------------------------------------------
__global__ __launch_bounds__(256) void chunk_outgn_kernel(
    const unsigned short* __restrict__ PcG, const unsigned short* __restrict__ OlG,
    const unsigned short* __restrict__ Sch, const float* __restrict__ s3G,
    const float* __restrict__ v_btc, const unsigned short* __restrict__ g_f,
    const float* __restrict__ gamma, const float* __restrict__ beta,
    unsigned short* __restrict__ yg)
{
  __shared__ float ST[64 * PAD];
  __shared__ float PB[64 * PAD];
  const int inst = blockIdx.x;
  const int bh = inst >> 4, c = inst & 15;
  const int b = bh >> 4, h = bh & 15;
  const int tid = threadIdx.x;
  const int tt = tid >> 4, jt = tid & 15;
  const size_t ob = (size_t)inst << 12;

#pragma unroll
  for (int q = 0; q < 4; ++q) {
    int idx = q * 1024 + tid * 4;
    int row = idx >> 6, col = idx & 63;
    ushort4 sv = *(const ushort4*)(Sch + ob + idx);
    ST[row * PAD + col] = bf2f(sv.x);     ST[row * PAD + col + 1] = bf2f(sv.y);
    ST[row * PAD + col + 2] = bf2f(sv.z); ST[row * PAD + col + 3] = bf2f(sv.w);
    ushort4 pv = *(const ushort4*)(PcG + ob + idx);
    PB[row * PAD + col] = bf2f(pv.x);     PB[row * PAD + col + 1] = bf2f(pv.y);
    PB[row * PAD + col + 2] = bf2f(pv.z); PB[row * PAD + col + 3] = bf2f(pv.w);
  }
  __syncthreads();

  float acc[4][4];
#pragma unroll
  for (int u = 0; u < 4; ++u) {
    ushort4 o4 = *(const ushort4*)(OlG + ob + (size_t)(4 * tt + u) * 64 + 4 * jt);
    acc[u][0] = bf2f(o4.x); acc[u][1] = bf2f(o4.y);
    acc[u][2] = bf2f(o4.z); acc[u][3] = bf2f(o4.w);
  }
#pragma unroll 4
  for (int pp = 0; pp < 64; ++pp) {
    float pv[4], sv[4];
#pragma unroll
    for (int u = 0; u < 4; ++u) pv[u] = PB[(4 * tt + u) * PAD + pp];
#pragma unroll
    for (int v = 0; v < 4; ++v) sv[v] = ST[pp * PAD + 4 * jt + v];
#pragma unroll
    for (int u = 0; u < 4; ++u)
#pragma unroll
      for (int v = 0; v < 4; ++v) acc[u][v] = fmaf(pv[u], sv[v], acc[u][v]);
  }

  const int colb = h * 64 + 4 * jt;
  float4 ga4 = *(const float4*)(gamma + colb);
  float4 be4 = *(const float4*)(beta + colb);

#pragma unroll
  for (int u = 0; u < 4; ++u) {
    float sum1 = acc[u][0] + acc[u][1] + acc[u][2] + acc[u][3];
    float sum2 = acc[u][0] * acc[u][0] + acc[u][1] * acc[u][1]
               + acc[u][2] * acc[u][2] + acc[u][3] * acc[u][3];
#pragma unroll
    for (int m = 1; m < 16; m <<= 1) {
      sum1 += __shfl_xor(sum1, m);
      sum2 += __shfl_xor(sum2, m);
    }
    const float mean = sum1 * (1.0f / 64.0f);
    const float var = sum2 * (1.0f / 64.0f) - mean * mean;
    const float rstd = rsqrtf(var + 0.00064f);
    const int tok = c * 64 + 4 * tt + u;
    const float s3 = s3G[(bh << 10) + tok];
    const size_t gaddr = ((size_t)(b * 1024 + tok) * 1024) + colb;
    float4 v4 = *(const float4*)(v_btc + gaddr);
    ushort4 g4b = *(const ushort4*)(g_f + gaddr);
    ushort4 ov;
    ov.x = f2bf(((acc[u][0] - mean) * rstd * ga4.x + be4.x + s3 * v4.x) * bf2f(g4b.x));
    ov.y = f2bf(((acc[u][1] - mean) * rstd * ga4.y + be4.y + s3 * v4.y) * bf2f(g4b.y));
    ov.z = f2bf(((acc[u][2] - mean) * rstd * ga4.z + be4.z + s3 * v4.z) * bf2f(g4b.z));
    ov.w = f2bf(((acc[u][3] - mean) * rstd * ga4.w + be4.w + s3 * v4.w) * bf2f(g4b.w));
    *(ushort4*)(yg + gaddr) = ov;
  }
}

// ---------------------------------------------------------------------------
extern "C" void kernel_launch(void* const* d_in, const int* in_sizes, int n_in,
                              void* d_out, int out_size, void* d_ws, size_t ws_size,
                              hipStream_t stream)
{
  (void)in_sizes; (void)n_in; (void)out_size;
  const float* x    = (const float*)d_in[0];
  const float* x_r  = (const float*)d_in[1];
  const float* x_w  = (const float*)d_in[2];
  const float* x_k  = (const float*)d_in[3];
  const float* x_v  = (const float*)d_in[4];
  const float* x_a  = (const float*)d_in[5];
  const float* x_g  = (const float*)d_in[6];
  const float* w0   = (const float*)d_in[7];
  const float* w1   = (const float*)d_in[8];
  const float* w2   = (const float*)d_in[9];
  const float* a0   = (const float*)d_in[10];
  const float* a1   = (const float*)d_in[11];
  const float* a2   = (const float*)d_in[12];
  const float* g1   = (const float*)d_in[16];
  const float* g2   = (const float*)d_in[17];
  const float* k_k  = (const float*)d_in[18];
  const float* k_a  = (const float*)d_in[19];
  const float* r_k  = (const float*)d_in[20];
  const float* Wr   = (const float*)d_in[21];
  const float* Wk   = (const float*)d_in[22];
  const float* Wv   = (const float*)d_in[23];
  const float* Wo   = (const float*)d_in[24];
  const float* ln_g = (const float*)d_in[25];
  const float* ln_b = (const float*)d_in[26];

  float* outp = (float*)d_out;
  float* vfirst = outp + (size_t)BB * TT * CCH;

  char* ws = (char*)d_ws;
  size_t off = 0;
  auto alloc = [&](size_t bytes) -> char* {
    char* p = ws + off;
    off += (bytes + 255) & ~(size_t)255;
    return p;
  };

  unsigned short* WrT = (unsigned short*)alloc(2097152);
  unsigned short* WkT = (unsigned short*)alloc(2097152);
  unsigned short* WvT = (unsigned short*)alloc(2097152);
  unsigned short* WoT = (unsigned short*)alloc(2097152);
  unsigned short* w1T = (unsigned short*)alloc(131072);
  unsigned short* w2T = (unsigned short*)alloc(131072);
  unsigned short* a1T = (unsigned short*)alloc(131072);
  unsigned short* a2T = (unsigned short*)alloc(131072);
  unsigned short* g1T = (unsigned short*)alloc(262144);
  unsigned short* g2T = (unsigned short*)alloc(262144);
  unsigned short* xrB = (unsigned short*)alloc(8388608);
  unsigned short* xwB = (unsigned short*)alloc(8388608);
  unsigned short* xkB = (unsigned short*)alloc(8388608);
  unsigned short* xvB = (unsigned short*)alloc(8388608);
  unsigned short* xaB = (unsigned short*)alloc(8388608);
  unsigned short* xgB = (unsigned short*)alloc(8388608);
  float* r_btc = (float*)alloc(16777216);
  float* k_btc = (float*)alloc(16777216);
  float* wraw  = (float*)alloc(16777216);
  float* araw  = (float*)alloc(16777216);
  unsigned short* gfB = (unsigned short*)alloc(8388608);
  unsigned short* OlG = (unsigned short*)alloc(8388608);
  unsigned short* DkG = (unsigned short*)alloc(8388608);
  float* LbG   = (float*)alloc(16777216);
  float* s3G   = (float*)alloc(262144);
  unsigned short* hwB = (unsigned short*)alloc(524288);
  unsigned short* haB = (unsigned short*)alloc(524288);
  unsigned short* hgB = (unsigned short*)alloc(1048576);
  unsigned short* ygB = (unsigned short*)alloc(8388608);

  // overlays (owners dead before the writer runs)
  unsigned short* McG = xrB;          // over xrB (dead after gemm_stage1)
  unsigned short* NcG = xkB;          // over xkB
  unsigned short* PcG = xaB;          // over xaB
  unsigned short* Sch = (unsigned short*)k_btc;  // k_btc dead after chunk_ops

  if (off > ws_size) return;

  dim3 blk(256);

  // transposes + mix in one launch
  prep_kernel<<<5248, blk, 0, stream>>>(
      x, x_r, x_w, x_k, x_v, x_a, x_g,
      xrB, xwB, xkB, xvB, xaB, xgB,
      Wr, Wk, Wv, Wo, WrT, WkT, WvT, WoT,
      w1, w2, a1, a2, g1, g2, w1T, w2T, a1T, a2T, g1T, g2T);

  // r/k/v GEMMs + lora1 in one launch; v straight into vfirst (output 1)
  gemm_stage1_kernel<<<896, blk, 0, stream>>>(
      xrB, xkB, xvB, WrT, WkT, WvT, r_btc, k_btc, vfirst,
      xwB, xaB, xgB, w1T, a1T, g1T, hwB, haB, hgB);

  // LoRA stage 2 (w/a/g) in one launch
  lora2_kernel<<<dim3(32, 8, 3), blk, 0, stream>>>(
      hwB, haB, hgB, w2T, a2T, g2T, wraw, araw, gfB);

  // chunked-DPLR scan phase 1 (postproc fused, 2 blocks/CU)
  constexpr int CHUNK_LDS = 7 * 64 * RS * 2 + 64 * 4 + 4 * 64 * 4;  // 65,792 B
  hipFuncSetAttribute((const void*)chunk_ops_kernel,
                      hipFuncAttributeMaxDynamicSharedMemorySize, CHUNK_LDS);
  chunk_ops_kernel<<<1024, blk, CHUNK_LDS, stream>>>(
      r_btc, k_btc, vfirst, wraw, araw, w0, a0, k_k, k_a, r_k,
      McG, NcG, PcG, OlG, DkG, s3G, LbG);

  chunk_scan_kernel<<<64, blk, 0, stream>>>(McG, NcG, Sch);

  chunk_outgn_kernel<<<1024, blk, 0, stream>>>(PcG, OlG, Sch, s3G, vfirst, gfB,
                                               ln_g, ln_b, ygB);

  gemm_out_kernel<<<dim3(32, 8), blk, 0, stream>>>(ygB, WoT, outp);
}

// Round 10
// 383.126 us; speedup vs baseline: 1.0936x; 1.0936x over previous
//
#include <hip/hip_runtime.h>
#include <hip/hip_bf16.h>
#include <math.h>

// Problem constants
#define BB 4
#define TT 1024
#define CCH 1024
#define HH 16
#define NNd 64
#define PAD 65      // fp32 LDS row pad (chunk_scan/outgn)
#define RS 72       // bf16 LDS row stride in shorts (144B = 9x16B, frag-aligned)
#define LBS 68      // bf16 L-matrix row stride in shorts (136B, 8B-aligned u4)

typedef short bf16x8 __attribute__((ext_vector_type(8)));
typedef float f32x4 __attribute__((ext_vector_type(4)));

__device__ __forceinline__ unsigned short f2bf(float f) {
  __hip_bfloat16 h = __float2bfloat16(f);
  return __builtin_bit_cast(unsigned short, h);
}
__device__ __forceinline__ float bf2f(unsigned short u) {
  unsigned int x = (unsigned int)u << 16;
  return __builtin_bit_cast(float, x);
}
__device__ __forceinline__ float sigmoidf_(float x) { return 1.0f / (1.0f + expf(-x)); }

// async global->LDS, 16B per lane; LDS dest must be wave-uniform base + 16*lane
__device__ __forceinline__ void gl2lds16(const unsigned short* g, unsigned short* l) {
  __builtin_amdgcn_global_load_lds(
      (const __attribute__((address_space(1))) unsigned int*)g,
      (__attribute__((address_space(3))) unsigned int*)l, 16, 0, 0);
}

// ---------------------------------------------------------------------------
// Transpose tile helper
// ---------------------------------------------------------------------------
__device__ __forceinline__ void transpose_tile(
    const float* __restrict__ in, unsigned short* __restrict__ out,
    int R, int Cc, int r0, int c0, unsigned short (*tile)[68], int t)
{
  const int rr = t >> 4;
  const int cc = (t & 15) * 4;
#pragma unroll
  for (int p = 0; p < 4; ++p) {
    int row = p * 16 + rr;
    float4 v = *(const float4*)(in + (size_t)(r0 + row) * Cc + c0 + cc);
    tile[row][cc]     = f2bf(v.x);
    tile[row][cc + 1] = f2bf(v.y);
    tile[row][cc + 2] = f2bf(v.z);
    tile[row][cc + 3] = f2bf(v.w);
  }
  __syncthreads();
#pragma unroll
  for (int p = 0; p < 4; ++p) {
    int row = p * 16 + rr;
    ushort4 o;
    o.x = tile[cc][row];
    o.y = tile[cc + 1][row];
    o.z = tile[cc + 2][row];
    o.w = tile[cc + 3][row];
    *(ushort4*)(out + (size_t)(c0 + row) * R + r0 + cc) = o;
  }
}

// ---------------------------------------------------------------------------
// prep_kernel: mix (blocks 0..4095) + big4 transposes (4096..5119)
//            + lora transposes (5120..5247), one launch.
// ---------------------------------------------------------------------------
__global__ __launch_bounds__(256) void prep_kernel(
    const float* __restrict__ x,
    const float* __restrict__ cr, const float* __restrict__ cw,
    const float* __restrict__ ck, const float* __restrict__ cv,
    const float* __restrict__ ca, const float* __restrict__ cg,
    unsigned short* __restrict__ xr, unsigned short* __restrict__ xw,
    unsigned short* __restrict__ xk, unsigned short* __restrict__ xv,
    unsigned short* __restrict__ xa, unsigned short* __restrict__ xg,
    const float* __restrict__ W0, const float* __restrict__ W1,
    const float* __restrict__ W2, const float* __restrict__ W3,
    unsigned short* __restrict__ T0, unsigned short* __restrict__ T1,
    unsigned short* __restrict__ T2, unsigned short* __restrict__ T3,
    const float* __restrict__ w1, const float* __restrict__ w2,
    const float* __restrict__ a1, const float* __restrict__ a2,
    const float* __restrict__ g1, const float* __restrict__ g2,
    unsigned short* __restrict__ w1T, unsigned short* __restrict__ w2T,
    unsigned short* __restrict__ a1T, unsigned short* __restrict__ a2T,
    unsigned short* __restrict__ g1T, unsigned short* __restrict__ g2T)
{
  __shared__ unsigned short tile[64][68];
  const int blk = blockIdx.x;
  const int tid = threadIdx.x;
  if (blk < 4096) {
    // ---- token-shift mix ----
    const size_t idx = ((size_t)blk * 256 + tid) * 4;
    const int c = (int)(idx & 1023);
    const int t = (int)((idx >> 10) & 1023);
    float4 xc = *(const float4*)(x + idx);
    float4 xp = make_float4(0.f, 0.f, 0.f, 0.f);
    if (t > 0) xp = *(const float4*)(x + idx - 1024);
    float4 dx = make_float4(xp.x - xc.x, xp.y - xc.y, xp.z - xc.z, xp.w - xc.w);
    auto st = [&](unsigned short* dst, const float* coef) {
      float4 w = *(const float4*)(coef + c);
      ushort4 o;
      o.x = f2bf(fmaf(dx.x, w.x, xc.x));
      o.y = f2bf(fmaf(dx.y, w.y, xc.y));
      o.z = f2bf(fmaf(dx.z, w.z, xc.z));
      o.w = f2bf(fmaf(dx.w, w.w, xc.w));
      *(ushort4*)(dst + idx) = o;
    };
    st(xr, cr); st(xw, cw); st(xk, ck); st(xv, cv); st(xa, ca); st(xg, cg);
  } else if (blk < 5120) {
    const int j = blk - 4096;
    const int z = j >> 8, rem = j & 255;
    const int ty = rem >> 4, tx = rem & 15;
    const float* src = (z == 0) ? W0 : (z == 1) ? W1 : (z == 2) ? W2 : W3;
    unsigned short* dst = (z == 0) ? T0 : (z == 1) ? T1 : (z == 2) ? T2 : T3;
    transpose_tile(src, dst, 1024, 1024, tx * 64, ty * 64, tile, tid);
  } else {
    const int i = blk - 5120;
    const float* src; unsigned short* dst; int R, C, rt, ct;
    if (i < 16)      { src = w1; dst = w1T; R = 1024; C = 64;   rt = i;      ct = 0; }
    else if (i < 32) { src = w2; dst = w2T; R = 64;   C = 1024; rt = 0;      ct = i - 16; }
    else if (i < 48) { src = a1; dst = a1T; R = 1024; C = 64;   rt = i - 32; ct = 0; }
    else if (i < 64) { src = a2; dst = a2T; R = 64;   C = 1024; rt = 0;      ct = i - 48; }
    else if (i < 96) { int k = i - 64; src = g1; dst = g1T; R = 1024; C = 128; rt = k >> 1; ct = k & 1; }
    else             { int k = i - 96; src = g2; dst = g2T; R = 128; C = 1024; rt = k & 1;  ct = k >> 1; }
    transpose_tile(src, dst, R, C, rt * 64, ct * 64, tile, tid);
  }
}

// ---------------------------------------------------------------------------
// gemm_stage1: blocks 0..767 = r/k/v big GEMMs (z=blk/256), 768..895 = lora1.
// r,k outputs bf16 (chunk_ops-only consumers); v output fp32 (vfirst).
// ---------------------------------------------------------------------------
__global__ __launch_bounds__(256) void gemm_stage1_kernel(
    const unsigned short* __restrict__ xrB, const unsigned short* __restrict__ xkB,
    const unsigned short* __restrict__ xvB,
    const unsigned short* __restrict__ WrT, const unsigned short* __restrict__ WkT,
    const unsigned short* __restrict__ WvT,
    unsigned short* __restrict__ r_btc, unsigned short* __restrict__ k_btc,
    float* __restrict__ v_btc,
    const unsigned short* __restrict__ xwB, const unsigned short* __restrict__ xaB,
    const unsigned short* __restrict__ xgB,
    const unsigned short* __restrict__ w1T, const unsigned short* __restrict__ a1T,
    const unsigned short* __restrict__ g1T,
    unsigned short* __restrict__ hwB, unsigned short* __restrict__ haB,
    unsigned short* __restrict__ hgB)
{
  constexpr int K = 1024, SK = 32;
  __shared__ __align__(16) unsigned short As[128 * SK];
  __shared__ __align__(16) unsigned short Bs[128 * SK];
  const int blk = blockIdx.x;
  const int tid = threadIdx.x;
  const int wv = tid >> 6, lane = tid & 63;
  const int fr = lane & 15, q = lane >> 4;
  const int arow = tid >> 2;
  const int akc = (tid & 3) * 8;

  if (blk < 768) {
    // ---- big3 GEMM: z selects r/k/v ----
    const int z = blk >> 8, rem = blk & 255;
    const int m0 = (rem & 31) * 128;
    const int n0 = (rem >> 5) * 128;
    const unsigned short* A = (z == 0) ? xrB : (z == 1) ? xkB : xvB;
    const unsigned short* BT = (z == 0) ? WrT : (z == 1) ? WkT : WvT;
    const int wave_m = wv >> 1, wave_n = wv & 1;

    f32x4 acc[4][4];
#pragma unroll
    for (int i = 0; i < 4; i++)
#pragma unroll
      for (int j = 0; j < 4; j++) acc[i][j] = (f32x4){0.f, 0.f, 0.f, 0.f};

    for (int k0 = 0; k0 < K; k0 += 32) {
#pragma unroll
      for (int i = 0; i < 2; ++i)
        gl2lds16(A + (size_t)(m0 + arow + i * 64) * K + k0 + akc, As + i * 2048 + wv * 512);
#pragma unroll
      for (int i = 0; i < 2; ++i)
        gl2lds16(BT + (size_t)(n0 + arow + i * 64) * K + k0 + akc, Bs + i * 2048 + wv * 512);
      __syncthreads();
      bf16x8 af[4], bfv[4];
#pragma unroll
      for (int i = 0; i < 4; i++)
        af[i] = *(const bf16x8*)(&As[(wave_m * 64 + i * 16 + fr) * SK + q * 8]);
#pragma unroll
      for (int j = 0; j < 4; j++)
        bfv[j] = *(const bf16x8*)(&Bs[(wave_n * 64 + j * 16 + fr) * SK + q * 8]);
#pragma unroll
      for (int i = 0; i < 4; i++)
#pragma unroll
        for (int j = 0; j < 4; j++)
          acc[i][j] = __builtin_amdgcn_mfma_f32_16x16x32_bf16(af[i], bfv[j], acc[i][j], 0, 0, 0);
      __syncthreads();
    }
#pragma unroll
    for (int i = 0; i < 4; i++)
#pragma unroll
      for (int j = 0; j < 4; j++) {
        const int mb = m0 + wave_m * 64 + i * 16 + q * 4;
        const int n = n0 + wave_n * 64 + j * 16 + fr;
#pragma unroll
        for (int r = 0; r < 4; r++) {
          if (z == 0)      r_btc[(size_t)(mb + r) * 1024 + n] = f2bf(acc[i][j][r]);
          else if (z == 1) k_btc[(size_t)(mb + r) * 1024 + n] = f2bf(acc[i][j][r]);
          else             v_btc[(size_t)(mb + r) * 1024 + n] = acc[i][j][r];
        }
      }
  } else {
    // ---- lora1: y=0 hw=tanh, y=1 ha, y=2/3 hg sigmoid halves ----
    const int j2 = blk - 768;
    const int y = j2 >> 5;
    const int m0 = (j2 & 31) * 128;
    const unsigned short* A  = (y == 0) ? xwB : (y == 1) ? xaB : xgB;
    const unsigned short* BT = (y == 0) ? w1T : (y == 1) ? a1T : (g1T + (size_t)(y - 2) * 64 * K);
    unsigned short* outb = (y == 0) ? hwB : (y == 1) ? haB : hgB;
    const int Nout = (y < 2) ? 64 : 128;
    const int ncol0 = (y < 2) ? 0 : (y - 2) * 64;

    f32x4 acc[2][4];
#pragma unroll
    for (int i = 0; i < 2; i++)
#pragma unroll
      for (int j = 0; j < 4; j++) acc[i][j] = (f32x4){0.f, 0.f, 0.f, 0.f};

    for (int k0 = 0; k0 < K; k0 += 32) {
#pragma unroll
      for (int i = 0; i < 2; ++i)
        gl2lds16(A + (size_t)(m0 + arow + i * 64) * K + k0 + akc, As + i * 2048 + wv * 512);
      gl2lds16(BT + (size_t)arow * K + k0 + akc, Bs + wv * 512);
      __syncthreads();
      bf16x8 af[2], bfv[4];
#pragma unroll
      for (int i = 0; i < 2; i++)
        af[i] = *(const bf16x8*)(&As[(wv * 32 + i * 16 + fr) * SK + q * 8]);
#pragma unroll
      for (int j = 0; j < 4; j++)
        bfv[j] = *(const bf16x8*)(&Bs[(j * 16 + fr) * SK + q * 8]);
#pragma unroll
      for (int i = 0; i < 2; i++)
#pragma unroll
        for (int j = 0; j < 4; j++)
          acc[i][j] = __builtin_amdgcn_mfma_f32_16x16x32_bf16(af[i], bfv[j], acc[i][j], 0, 0, 0);
      __syncthreads();
    }
#pragma unroll
    for (int i = 0; i < 2; i++)
#pragma unroll
      for (int j = 0; j < 4; j++) {
        const int mb = m0 + wv * 32 + i * 16 + q * 4;
        const int n = ncol0 + j * 16 + fr;
#pragma unroll
        for (int r = 0; r < 4; r++) {
          float val = acc[i][j][r];
          if (y == 0) val = tanhf(val);
          else if (y >= 2) val = sigmoidf_(val);
          outb[(size_t)(mb + r) * Nout + n] = f2bf(val);
        }
      }
  }
}

// z-batched LoRA-2 GEMMs -> all bf16 outputs (wraw, araw, g).
__global__ __launch_bounds__(256) void lora2_kernel(
    const unsigned short* __restrict__ hwB, const unsigned short* __restrict__ haB,
    const unsigned short* __restrict__ hgB,
    const unsigned short* __restrict__ w2T, const unsigned short* __restrict__ a2T,
    const unsigned short* __restrict__ g2T,
    unsigned short* __restrict__ wraw, unsigned short* __restrict__ araw,
    unsigned short* __restrict__ gfB)
{
  constexpr int N = 1024, SK = 32;
  __shared__ __align__(16) unsigned short As[128 * SK];
  __shared__ __align__(16) unsigned short Bs[128 * SK];
  const int z = blockIdx.z;
  const unsigned short* A = (z == 0) ? hwB : (z == 1) ? haB : hgB;
  const unsigned short* BT = (z == 0) ? w2T : (z == 1) ? a2T : g2T;
  unsigned short* out = (z == 0) ? wraw : (z == 1) ? araw : gfB;
  const int K = (z == 2) ? 128 : 64;

  const int tid = threadIdx.x;
  const int wv = tid >> 6, lane = tid & 63;
  const int fr = lane & 15, q = lane >> 4;
  const int wave_m = wv >> 1, wave_n = wv & 1;
  const int m0 = blockIdx.x * 128;
  const int n0 = blockIdx.y * 128;

  f32x4 acc[4][4];
#pragma unroll
  for (int i = 0; i < 4; i++)
#pragma unroll
    for (int j = 0; j < 4; j++) acc[i][j] = (f32x4){0.f, 0.f, 0.f, 0.f};

  const int arow = tid >> 2;
  const int akc = (tid & 3) * 8;

  for (int k0 = 0; k0 < K; k0 += 32) {
#pragma unroll
    for (int i = 0; i < 2; ++i)
      gl2lds16(A + (size_t)(m0 + arow + i * 64) * K + k0 + akc, As + i * 2048 + wv * 512);
#pragma unroll
    for (int i = 0; i < 2; ++i)
      gl2lds16(BT + (size_t)(n0 + arow + i * 64) * K + k0 + akc, Bs + i * 2048 + wv * 512);
    __syncthreads();
    bf16x8 af[4], bfv[4];
#pragma unroll
    for (int i = 0; i < 4; i++)
      af[i] = *(const bf16x8*)(&As[(wave_m * 64 + i * 16 + fr) * SK + q * 8]);
#pragma unroll
    for (int j = 0; j < 4; j++)
      bfv[j] = *(const bf16x8*)(&Bs[(wave_n * 64 + j * 16 + fr) * SK + q * 8]);
#pragma unroll
    for (int i = 0; i < 4; i++)
#pragma unroll
      for (int j = 0; j < 4; j++)
        acc[i][j] = __builtin_amdgcn_mfma_f32_16x16x32_bf16(af[i], bfv[j], acc[i][j], 0, 0, 0);
    __syncthreads();
  }
#pragma unroll
  for (int i = 0; i < 4; i++)
#pragma unroll
    for (int j = 0; j < 4; j++) {
      const int mb = m0 + wave_m * 64 + i * 16 + q * 4;
      const int n = n0 + wave_n * 64 + j * 16 + fr;
#pragma unroll
      for (int r = 0; r < 4; r++)
        out[(size_t)(mb + r) * N + n] = f2bf(acc[i][j][r]);
    }
}

// Final projection GEMM (yg @ WoT -> out fp32)
__global__ __launch_bounds__(256) void gemm_out_kernel(
    const unsigned short* __restrict__ A,
    const unsigned short* __restrict__ BT,
    float* __restrict__ out)
{
  constexpr int K = 1024, N = 1024, SK = 32;
  __shared__ __align__(16) unsigned short As[128 * SK];
  __shared__ __align__(16) unsigned short Bs[128 * SK];
  const int tid = threadIdx.x;
  const int wv = tid >> 6, lane = tid & 63;
  const int fr = lane & 15, q = lane >> 4;
  const int wave_m = wv >> 1, wave_n = wv & 1;
  const int m0 = blockIdx.x * 128;
  const int n0 = blockIdx.y * 128;

  f32x4 acc[4][4];
#pragma unroll
  for (int i = 0; i < 4; i++)
#pragma unroll
    for (int j = 0; j < 4; j++) acc[i][j] = (f32x4){0.f, 0.f, 0.f, 0.f};

  const int arow = tid >> 2;
  const int akc = (tid & 3) * 8;

  for (int k0 = 0; k0 < K; k0 += 32) {
#pragma unroll
    for (int i = 0; i < 2; ++i)
      gl2lds16(A + (size_t)(m0 + arow + i * 64) * K + k0 + akc, As + i * 2048 + wv * 512);
#pragma unroll
    for (int i = 0; i < 2; ++i)
      gl2lds16(BT + (size_t)(n0 + arow + i * 64) * K + k0 + akc, Bs + i * 2048 + wv * 512);
    __syncthreads();
    bf16x8 af[4], bfv[4];
#pragma unroll
    for (int i = 0; i < 4; i++)
      af[i] = *(const bf16x8*)(&As[(wave_m * 64 + i * 16 + fr) * SK + q * 8]);
#pragma unroll
    for (int j = 0; j < 4; j++)
      bfv[j] = *(const bf16x8*)(&Bs[(wave_n * 64 + j * 16 + fr) * SK + q * 8]);
#pragma unroll
    for (int i = 0; i < 4; i++)
#pragma unroll
      for (int j = 0; j < 4; j++)
        acc[i][j] = __builtin_amdgcn_mfma_f32_16x16x32_bf16(af[i], bfv[j], acc[i][j], 0, 0, 0);
    __syncthreads();
  }
#pragma unroll
  for (int i = 0; i < 4; i++)
#pragma unroll
    for (int j = 0; j < 4; j++) {
      const int mb = m0 + wave_m * 64 + i * 16 + q * 4;
      const int n = n0 + wave_n * 64 + j * 16 + fr;
#pragma unroll
      for (int r = 0; r < 4; r++)
        out[(size_t)(mb + r) * N + n] = acc[i][j][r];
    }
}

// ---------------------------------------------------------------------------
// Phase 1 (MFMA): per-(bh,chunk) chunked-DPLR operators, postproc FUSED.
// HBM-BW-bound: inputs r/k/wraw/araw bf16 (v fp32 = vfirst). L matrix in LDS
// bf16 (R8 config). 1 expf + 1 rcp per token.
// ---------------------------------------------------------------------------
__global__ __launch_bounds__(256, 2) void chunk_ops_kernel(
    const unsigned short* __restrict__ r_btc, const unsigned short* __restrict__ k_btc,
    const float* __restrict__ v_btc, const unsigned short* __restrict__ wraw,
    const unsigned short* __restrict__ araw,
    const float* __restrict__ w0, const float* __restrict__ a0,
    const float* __restrict__ k_k, const float* __restrict__ k_a,
    const float* __restrict__ r_k,
    unsigned short* __restrict__ McG, unsigned short* __restrict__ NcG,
    unsigned short* __restrict__ PcG, unsigned short* __restrict__ OlG,
    unsigned short* __restrict__ DkG, float* __restrict__ s3G)
{
  extern __shared__ char smraw[];
  unsigned short* AHb  = (unsigned short*)smraw;   // S1: Ahat -> XTb
  unsigned short* RHb  = AHb + 64 * RS;            // S2: Rhat (bf16, thru E)
  unsigned short* BPb  = RHb + 64 * RS;            // S3: Bp -> LKA/Y -> QTb
  unsigned short* KPb  = BPb + 64 * RS;            // S4: Kp -> DBR
  unsigned short* BPTb = KPb + 64 * RS;            // S5: Btil^T [i][t]
  unsigned short* KPTb = BPTb + 64 * RS;           // S6: Ktil^T [i][t]
  unsigned short* VSTb = KPTb + 64 * RS;           // S7: V^T [n][t]
  unsigned short* LBb  = VSTb + 64 * RS;           // S8: LBA bf16 (s68)
  float* GLs = (float*)(LBb + 64 * LBS);           // [64] total log-decay
  float* SS  = GLs + 64;                           // [4][64] strip sums
  unsigned short* XTb = AHb;                       // overlay after solve
  unsigned short* LKb = BPb;                       // overlay after Gram
  unsigned short* QTb = BPb;                       // overlay after Qloc
  unsigned short* DBb = KPb;                       // overlay after Gram

  const int inst = blockIdx.x;
  const int bh = inst >> 4, c = inst & 15;
  const int b = bh >> 4, h = bh & 15;
  const int tid = threadIdx.x;
  const int lane = tid & 63;
  const int wv = tid >> 6;
  const int jl = lane;
  const int ch = h * 64 + jl;
  const size_t base = ((size_t)(b * 1024 + c * 64) * 1024) + ch;

  const float p_w0 = w0[ch], p_a0 = a0[ch];
  const float p_kk = k_k[ch], p_ka = k_a[ch], p_rk = r_k[ch];
  const float EM = 0.60653065971263342f;  // e^{-0.5}

  // ---- pass 1: log-decay for my 16 rows + strip sum ----
  float lwv[16];
  {
    float run = 0.f;
#pragma unroll
    for (int u = 0; u < 16; ++u) {
      const float wr = bf2f(wraw[base + (size_t)(16 * wv + u) * 1024]);
      const float lw = -EM * sigmoidf_(p_w0 + wr);
      lwv[u] = lw; run += lw;
    }
    SS[wv * 64 + jl] = run;
  }
  __syncthreads();
  const float s0 = SS[0 * 64 + jl], s1 = SS[1 * 64 + jl];
  const float s2 = SS[2 * 64 + jl], s3s = SS[3 * 64 + jl];
  const float goff = (wv > 0 ? s0 : 0.f) + (wv > 1 ? s1 : 0.f) + (wv > 2 ? s2 : 0.f);
  const float gl = s0 + s1 + s2 + s3s;
  if (wv == 0) GLs[jl] = gl;

  // ---- pass 2: per-token transforms + factor matrices ----
  {
    float grun = goff;
    float e_prev = expf(goff);          // exp(g_{t-1})
    const float e_gl = expf(gl);
#pragma unroll
    for (int u = 0; u < 16; ++u) {
      const int t = 16 * wv + u;
      const size_t gi = base + (size_t)t * 1024;
      const float kv = bf2f(k_btc[gi]), rv = bf2f(r_btc[gi]);
      const float vv = v_btc[gi], ar = bf2f(araw[gi]);
      const float av = sigmoidf_(p_a0 + ar);
      const float kkx = kv * p_kk;
      float ssq = kkx * kkx;
#pragma unroll
      for (int m = 1; m < 64; m <<= 1) ssq += __shfl_xor(ssq, m);
      const float scale = 1.0f / fmaxf(sqrtf(ssq), 1e-12f);
      const float kkn = kkx * scale;
      const float bb = kkn * av;
      const float kmod = kv * (1.0f + (av - 1.0f) * p_ka);
      float s3 = rv * kmod * p_rk;
#pragma unroll
      for (int m = 1; m < 64; m <<= 1) s3 += __shfl_xor(s3, m);
      if (jl == 0) s3G[(bh << 10) + (c << 6) + t] = s3;
      grun += lwv[u];
      const float e_gu = expf(grun);                     // exp(g_u), <= 1
      const float em = __builtin_amdgcn_rcpf(e_gu);      // exp(-g_u)
      const float egl = e_gl * em;                       // exp(gl-g_u) <= 1
      AHb[t * RS + jl] = f2bf(-kkn * e_prev);
      BPb[t * RS + jl] = f2bf(bb * em);
      KPb[t * RS + jl] = f2bf(kmod * em);
      BPTb[jl * RS + t] = f2bf(bb * egl);
      KPTb[jl * RS + t] = f2bf(kmod * egl);
      RHb[t * RS + jl] = f2bf(rv * e_gu);
      VSTb[jl * RS + t] = f2bf(vv);
      e_prev = e_gu;
    }
  }
  __syncthreads();

  const int fr = lane & 15, q = lane >> 4;
  const int i0 = wv * 16;

  // ---- Gram products via MFMA: LBA, LKA, DBR, DKR(->global) ----
  {
    f32x4 aLB[4], aLK[4], aDB[4], aDK[4];
#pragma unroll
    for (int j = 0; j < 4; ++j) {
      aLB[j] = (f32x4){0.f, 0.f, 0.f, 0.f}; aLK[j] = (f32x4){0.f, 0.f, 0.f, 0.f};
      aDB[j] = (f32x4){0.f, 0.f, 0.f, 0.f}; aDK[j] = (f32x4){0.f, 0.f, 0.f, 0.f};
    }
#pragma unroll
    for (int ks = 0; ks < 2; ++ks) {
      const int ko = ks * 32 + q * 8;
      bf16x8 fA = *(const bf16x8*)(AHb + (i0 + fr) * RS + ko);
      bf16x8 fR = *(const bf16x8*)(RHb + (i0 + fr) * RS + ko);
#pragma unroll
      for (int j = 0; j < 4; ++j) {
        bf16x8 fB = *(const bf16x8*)(BPb + (j * 16 + fr) * RS + ko);
        bf16x8 fK = *(const bf16x8*)(KPb + (j * 16 + fr) * RS + ko);
        aLB[j] = __builtin_amdgcn_mfma_f32_16x16x32_bf16(fA, fB, aLB[j], 0, 0, 0);
        aLK[j] = __builtin_amdgcn_mfma_f32_16x16x32_bf16(fA, fK, aLK[j], 0, 0, 0);
        aDB[j] = __builtin_amdgcn_mfma_f32_16x16x32_bf16(fR, fB, aDB[j], 0, 0, 0);
        aDK[j] = __builtin_amdgcn_mfma_f32_16x16x32_bf16(fR, fK, aDK[j], 0, 0, 0);
      }
    }
    __syncthreads();   // all Gram fragment reads done before overlay stores
#pragma unroll
    for (int j = 0; j < 4; ++j) {
      const int s = j * 16 + fr;
#pragma unroll
      for (int r = 0; r < 4; ++r) {
        const int t = i0 + q * 4 + r;
        LBb[t * LBS + s] = f2bf((s < t) ? aLB[j][r] : 0.f);
        LKb[t * RS + s] = f2bf((s < t) ? aLK[j][r] : 0.f);
        DBb[t * RS + s] = f2bf((s <= t) ? aDB[j][r] : 0.f);
        DkG[(size_t)inst * 4096 + t * 64 + s] = f2bf((s <= t) ? aDK[j][r] : 0.f);
      }
    }
  }
  __syncthreads();

  // ---- triangular solve (I-LBA)[X|Y] = [Ahat|LKA] (fp32, 128 threads) ----
  if (tid < 128) {
    const int jc = lane;
    const bool isX = (wv == 0);
    float x[64];
#pragma unroll
    for (int t = 0; t < 64; ++t)
      x[t] = bf2f(isX ? AHb[t * RS + jc] : LKb[t * RS + jc]);
#pragma unroll
    for (int t = 1; t < 64; ++t) {
      float a0r = 0.f, a1r = 0.f, a2r = 0.f, a3r = 0.f;
      const unsigned short* lr = LBb + t * LBS;
#pragma unroll
      for (int s = 0; s + 4 <= t; s += 4) {
        ushort4 l4 = *(const ushort4*)(lr + s);
        a0r = fmaf(bf2f(l4.x), x[s], a0r);     a1r = fmaf(bf2f(l4.y), x[s + 1], a1r);
        a2r = fmaf(bf2f(l4.z), x[s + 2], a2r); a3r = fmaf(bf2f(l4.w), x[s + 3], a3r);
      }
#pragma unroll
      for (int s = t & ~3; s < t; ++s) a0r = fmaf(bf2f(lr[s]), x[s], a0r);
      x[t] += (a0r + a1r) + (a2r + a3r);
    }
    if (isX) {
#pragma unroll
      for (int t = 0; t < 64; t += 2) {
        unsigned int pk = (unsigned int)f2bf(x[t]) | ((unsigned int)f2bf(x[t + 1]) << 16);
        *(unsigned int*)(XTb + jc * RS + t) = pk;
      }
    } else {
#pragma unroll
      for (int t = 0; t < 64; ++t) LKb[t * RS + jc] = f2bf(x[t]);
    }
  }
  __syncthreads();

  // ---- prefetch DKR fragments from global (L2-hot: our own writes) ----
  bf16x8 fDK0, fDK1;
  {
    const unsigned short* dkp = DkG + (size_t)inst * 4096 + (i0 + fr) * 64 + q * 8;
    fDK0 = *(const bf16x8*)(dkp);
    fDK1 = *(const bf16x8*)(dkp + 32);
  }

  // ---- Qloc = Y V (MFMA) ----
  {
    f32x4 qa[4];
#pragma unroll
    for (int j = 0; j < 4; ++j) qa[j] = (f32x4){0.f, 0.f, 0.f, 0.f};
#pragma unroll
    for (int ks = 0; ks < 2; ++ks) {
      const int ko = ks * 32 + q * 8;
      bf16x8 fY = *(const bf16x8*)(LKb + (i0 + fr) * RS + ko);
#pragma unroll
      for (int j = 0; j < 4; ++j) {
        bf16x8 fV = *(const bf16x8*)(VSTb + (j * 16 + fr) * RS + ko);
        qa[j] = __builtin_amdgcn_mfma_f32_16x16x32_bf16(fY, fV, qa[j], 0, 0, 0);
      }
    }
    __syncthreads();   // Qloc reads of LKb done -> overlay QTb
#pragma unroll
    for (int j = 0; j < 4; ++j) {
      const int n = j * 16 + fr;
      ushort4 pk;
      pk.x = f2bf(qa[j][0]); pk.y = f2bf(qa[j][1]);
      pk.z = f2bf(qa[j][2]); pk.w = f2bf(qa[j][3]);
      *(ushort4*)(QTb + n * RS + i0 + q * 4) = pk;
    }
  }
  __syncthreads();

  // ---- final operators: Mc, Ncc, Pc, Oloc (MFMA) -> global bf16 ----
  {
    f32x4 mA[4], nA[4], pA[4], oA[4];
#pragma unroll
    for (int j = 0; j < 4; ++j) {
      mA[j] = (f32x4){0.f, 0.f, 0.f, 0.f}; nA[j] = (f32x4){0.f, 0.f, 0.f, 0.f};
      pA[j] = (f32x4){0.f, 0.f, 0.f, 0.f}; oA[j] = (f32x4){0.f, 0.f, 0.f, 0.f};
    }
#pragma unroll
    for (int ks = 0; ks < 2; ++ks) {
      const int ko = ks * 32 + q * 8;
      bf16x8 fBT = *(const bf16x8*)(BPTb + (i0 + fr) * RS + ko);
      bf16x8 fKT = *(const bf16x8*)(KPTb + (i0 + fr) * RS + ko);
      bf16x8 fDB = *(const bf16x8*)(DBb + (i0 + fr) * RS + ko);
      bf16x8 fDK = ks ? fDK1 : fDK0;
#pragma unroll
      for (int j = 0; j < 4; ++j) {
        bf16x8 fXT = *(const bf16x8*)(XTb + (j * 16 + fr) * RS + ko);
        bf16x8 fQT = *(const bf16x8*)(QTb + (j * 16 + fr) * RS + ko);
        bf16x8 fVT = *(const bf16x8*)(VSTb + (j * 16 + fr) * RS + ko);
        mA[j] = __builtin_amdgcn_mfma_f32_16x16x32_bf16(fBT, fXT, mA[j], 0, 0, 0);
        nA[j] = __builtin_amdgcn_mfma_f32_16x16x32_bf16(fBT, fQT, nA[j], 0, 0, 0);
        nA[j] = __builtin_amdgcn_mfma_f32_16x16x32_bf16(fKT, fVT, nA[j], 0, 0, 0);
        pA[j] = __builtin_amdgcn_mfma_f32_16x16x32_bf16(fDB, fXT, pA[j], 0, 0, 0);
        oA[j] = __builtin_amdgcn_mfma_f32_16x16x32_bf16(fDB, fQT, oA[j], 0, 0, 0);
        oA[j] = __builtin_amdgcn_mfma_f32_16x16x32_bf16(fDK, fVT, oA[j], 0, 0, 0);
      }
    }
    const size_t ob = (size_t)inst * 4096;
    float eg[4];
#pragma unroll
    for (int r = 0; r < 4; ++r) eg[r] = expf(GLs[i0 + q * 4 + r]);
#pragma unroll
    for (int j = 0; j < 4; ++j) {
      const int col = j * 16 + fr;
#pragma unroll
      for (int r = 0; r < 4; ++r) {
        const int row = i0 + q * 4 + r;
        const size_t oi = ob + (size_t)row * 64 + col;
        McG[oi] = f2bf(mA[j][r] + (row == col ? eg[r] : 0.f));
        NcG[oi] = f2bf(nA[j][r]);
        PcG[oi] = f2bf(pA[j][r] + bf2f(RHb[row * RS + col]));
        OlG[oi] = f2bf(oA[j][r]);
      }
    }
  }
}

// ---------------------------------------------------------------------------
// Phase 2: sequential chunk-state propagation per (b,h): ST' = Mc ST + Ncc.
// ---------------------------------------------------------------------------
__global__ __launch_bounds__(256) void chunk_scan_kernel(
    const unsigned short* __restrict__ McG, const unsigned short* __restrict__ NcG,
    unsigned short* __restrict__ Sch)
{
  __shared__ float ST[64 * PAD];
  __shared__ float MB[64 * PAD];
  const int bh = blockIdx.x;
  const int tid = threadIdx.x;
  const int it = tid >> 4, jt = tid & 15;

#pragma unroll
  for (int q = 0; q < 16; ++q) {
    int idx = q * 256 + tid;
    ST[(idx >> 6) * PAD + (idx & 63)] = 0.f;
  }
  __syncthreads();

  for (int c = 0; c < 16; ++c) {
    const size_t ob = ((((size_t)bh << 4) + c) << 12);
#pragma unroll
    for (int q = 0; q < 4; ++q) {
      int idx = q * 1024 + tid * 4;
      int row = idx >> 6, col = idx & 63;
      ushort4 sv;
      sv.x = f2bf(ST[row * PAD + col]);     sv.y = f2bf(ST[row * PAD + col + 1]);
      sv.z = f2bf(ST[row * PAD + col + 2]); sv.w = f2bf(ST[row * PAD + col + 3]);
      *(ushort4*)(Sch + ob + idx) = sv;
      ushort4 mv = *(const ushort4*)(McG + ob + idx);
      MB[row * PAD + col] = bf2f(mv.x);     MB[row * PAD + col + 1] = bf2f(mv.y);
      MB[row * PAD + col + 2] = bf2f(mv.z); MB[row * PAD + col + 3] = bf2f(mv.w);
    }
    __syncthreads();
    float acc[4][4];
#pragma unroll
    for (int u = 0; u < 4; ++u) {
      ushort4 n4 = *(const ushort4*)(NcG + ob + (size_t)(4 * it + u) * 64 + 4 * jt);
      acc[u][0] = bf2f(n4.x); acc[u][1] = bf2f(n4.y);
      acc[u][2] = bf2f(n4.z); acc[u][3] = bf2f(n4.w);
    }
#pragma unroll 4
    for (int pp = 0; pp < 64; ++pp) {
      float mv[4], sv[4];
#pragma unroll
      for (int u = 0; u < 4; ++u) mv[u] = MB[(4 * it + u) * PAD + pp];
#pragma unroll
      for (int v = 0; v < 4; ++v) sv[v] = ST[pp * PAD + 4 * jt + v];
#pragma unroll
      for (int u = 0; u < 4; ++u)
#pragma unroll
        for (int v = 0; v < 4; ++v) acc[u][v] = fmaf(mv[u], sv[v], acc[u][v]);
    }
    __syncthreads();
#pragma unroll
    for (int u = 0; u < 4; ++u)
#pragma unroll
      for (int v = 0; v < 4; ++v) ST[(4 * it + u) * PAD + 4 * jt + v] = acc[u][v];
    __syncthreads();
  }
}

// ---------------------------------------------------------------------------
// Phase 3 + GroupNorm fused: Out = Pc ST + Oloc; per-row norm; + s3*v; *g.
// ---------------------------------------------------------------------------
__global__ __launch_bounds__(256) void chunk_outgn_kernel(
    const unsigned short* __restrict__ PcG, const unsigned short* __restrict__ OlG,
    const unsigned short* __restrict__ Sch, const float* __restrict__ s3G,
    const float* __restrict__ v_btc, const unsigned short* __restrict__ g_f,
    const float* __restrict__ gamma, const float* __restrict__ beta,
    unsigned short* __restrict__ yg)
{
  __shared__ float ST[64 * PAD];
  __shared__ float PB[64 * PAD];
  const int inst = blockIdx.x;
  const int bh = inst >> 4, c = inst & 15;
  const int b = bh >> 4, h = bh & 15;
  const int tid = threadIdx.x;
  const int tt = tid >> 4, jt = tid & 15;
  const size_t ob = (size_t)inst << 12;

#pragma unroll
  for (int q = 0; q < 4; ++q) {
    int idx = q * 1024 + tid * 4;
    int row = idx >> 6, col = idx & 63;
    ushort4 sv = *(const ushort4*)(Sch + ob + idx);
    ST[row * PAD + col] = bf2f(sv.x);     ST[row * PAD + col + 1] = bf2f(sv.y);
    ST[row * PAD + col + 2] = bf2f(sv.z); ST[row * PAD + col + 3] = bf2f(sv.w);
    ushort4 pv = *(const ushort4*)(PcG + ob + idx);
    PB[row * PAD + col] = bf2f(pv.x);     PB[row * PAD + col + 1] = bf2f(pv.y);
    PB[row * PAD + col + 2] = bf2f(pv.z); PB[row * PAD + col + 3] = bf2f(pv.w);
  }
  __syncthreads();

  float acc[4][4];
#pragma unroll
  for (int u = 0; u < 4; ++u) {
    ushort4 o4 = *(const ushort4*)(OlG + ob + (size_t)(4 * tt + u) * 64 + 4 * jt);
    acc[u][0] = bf2f(o4.x); acc[u][1] = bf2f(o4.y);
    acc[u][2] = bf2f(o4.z); acc[u][3] = bf2f(o4.w);
  }
#pragma unroll 4
  for (int pp = 0; pp < 64; ++pp) {
    float pv[4], sv[4];
#pragma unroll
    for (int u = 0; u < 4; ++u) pv[u] = PB[(4 * tt + u) * PAD + pp];
#pragma unroll
    for (int v = 0; v < 4; ++v) sv[v] = ST[pp * PAD + 4 * jt + v];
#pragma unroll
    for (int u = 0; u < 4; ++u)
#pragma unroll
      for (int v = 0; v < 4; ++v) acc[u][v] = fmaf(pv[u], sv[v], acc[u][v]);
  }

  const int colb = h * 64 + 4 * jt;
  float4 ga4 = *(const float4*)(gamma + colb);
  float4 be4 = *(const float4*)(beta + colb);

#pragma unroll
  for (int u = 0; u < 4; ++u) {
    float sum1 = acc[u][0] + acc[u][1] + acc[u][2] + acc[u][3];
    float sum2 = acc[u][0] * acc[u][0] + acc[u][1] * acc[u][1]
               + acc[u][2] * acc[u][2] + acc[u][3] * acc[u][3];
#pragma unroll
    for (int m = 1; m < 16; m <<= 1) {
      sum1 += __shfl_xor(sum1, m);
      sum2 += __shfl_xor(sum2, m);
    }
    const float mean = sum1 * (1.0f / 64.0f);
    const float var = sum2 * (1.0f / 64.0f) - mean * mean;
    const float rstd = rsqrtf(var + 0.00064f);
    const int tok = c * 64 + 4 * tt + u;
    const float s3 = s3G[(bh << 10) + tok];
    const size_t gaddr = ((size_t)(b * 1024 + tok) * 1024) + colb;
    float4 v4 = *(const float4*)(v_btc + gaddr);
    ushort4 g4b = *(const ushort4*)(g_f + gaddr);
    ushort4 ov;
    ov.x = f2bf(((acc[u][0] - mean) * rstd * ga4.x + be4.x + s3 * v4.x) * bf2f(g4b.x));
    ov.y = f2bf(((acc[u][1] - mean) * rstd * ga4.y + be4.y + s3 * v4.y) * bf2f(g4b.y));
    ov.z = f2bf(((acc[u][2] - mean) * rstd * ga4.z + be4.z + s3 * v4.z) * bf2f(g4b.z));
    ov.w = f2bf(((acc[u][3] - mean) * rstd * ga4.w + be4.w + s3 * v4.w) * bf2f(g4b.w));
    *(ushort4*)(yg + gaddr) = ov;
  }
}

// ---------------------------------------------------------------------------
extern "C" void kernel_launch(void* const* d_in, const int* in_sizes, int n_in,
                              void* d_out, int out_size, void* d_ws, size_t ws_size,
                              hipStream_t stream)
{
  (void)in_sizes; (void)n_in; (void)out_size;
  const float* x    = (const float*)d_in[0];
  const float* x_r  = (const float*)d_in[1];
  const float* x_w  = (const float*)d_in[2];
  const float* x_k  = (const float*)d_in[3];
  const float* x_v  = (const float*)d_in[4];
  const float* x_a  = (const float*)d_in[5];
  const float* x_g  = (const float*)d_in[6];
  const float* w0   = (const float*)d_in[7];
  const float* w1   = (const float*)d_in[8];
  const float* w2   = (const float*)d_in[9];
  const float* a0   = (const float*)d_in[10];
  const float* a1   = (const float*)d_in[11];
  const float* a2   = (const float*)d_in[12];
  const float* g1   = (const float*)d_in[16];
  const float* g2   = (const float*)d_in[17];
  const float* k_k  = (const float*)d_in[18];
  const float* k_a  = (const float*)d_in[19];
  const float* r_k  = (const float*)d_in[20];
  const float* Wr   = (const float*)d_in[21];
  const float* Wk   = (const float*)d_in[22];
  const float* Wv   = (const float*)d_in[23];
  const float* Wo   = (const float*)d_in[24];
  const float* ln_g = (const float*)d_in[25];
  const float* ln_b = (const float*)d_in[26];

  float* outp = (float*)d_out;
  float* vfirst = outp + (size_t)BB * TT * CCH;

  char* ws = (char*)d_ws;
  size_t off = 0;
  auto alloc = [&](size_t bytes) -> char* {
    char* p = ws + off;
    off += (bytes + 255) & ~(size_t)255;
    return p;
  };

  unsigned short* WrT = (unsigned short*)alloc(2097152);
  unsigned short* WkT = (unsigned short*)alloc(2097152);
  unsigned short* WvT = (unsigned short*)alloc(2097152);
  unsigned short* WoT = (unsigned short*)alloc(2097152);
  unsigned short* w1T = (unsigned short*)alloc(131072);
  unsigned short* w2T = (unsigned short*)alloc(131072);
  unsigned short* a1T = (unsigned short*)alloc(131072);
  unsigned short* a2T = (unsigned short*)alloc(131072);
  unsigned short* g1T = (unsigned short*)alloc(262144);
  unsigned short* g2T = (unsigned short*)alloc(262144);
  unsigned short* xrB = (unsigned short*)alloc(8388608);
  unsigned short* xwB = (unsigned short*)alloc(8388608);
  unsigned short* xkB = (unsigned short*)alloc(8388608);
  unsigned short* xvB = (unsigned short*)alloc(8388608);
  unsigned short* xaB = (unsigned short*)alloc(8388608);
  unsigned short* xgB = (unsigned short*)alloc(8388608);
  unsigned short* r_btc = (unsigned short*)alloc(8388608);
  unsigned short* k_btc = (unsigned short*)alloc(8388608);
  unsigned short* wraw  = (unsigned short*)alloc(8388608);
  unsigned short* araw  = (unsigned short*)alloc(8388608);
  unsigned short* gfB = (unsigned short*)alloc(8388608);
  unsigned short* OlG = (unsigned short*)alloc(8388608);
  unsigned short* DkG = (unsigned short*)alloc(8388608);
  float* s3G   = (float*)alloc(262144);
  unsigned short* hwB = (unsigned short*)alloc(524288);
  unsigned short* haB = (unsigned short*)alloc(524288);
  unsigned short* hgB = (unsigned short*)alloc(1048576);
  unsigned short* ygB = (unsigned short*)alloc(8388608);

  // overlays (owners dead before the writer runs)
  unsigned short* McG = xrB;          // over xrB (dead after gemm_stage1)
  unsigned short* NcG = xkB;          // over xkB
  unsigned short* PcG = xaB;          // over xaB
  unsigned short* Sch = k_btc;        // k_btc dead after chunk_ops

  if (off > ws_size) return;

  dim3 blk(256);

  // transposes + mix in one launch
  prep_kernel<<<5248, blk, 0, stream>>>(
      x, x_r, x_w, x_k, x_v, x_a, x_g,
      xrB, xwB, xkB, xvB, xaB, xgB,
      Wr, Wk, Wv, Wo, WrT, WkT, WvT, WoT,
      w1, w2, a1, a2, g1, g2, w1T, w2T, a1T, a2T, g1T, g2T);

  // r/k/v GEMMs + lora1 in one launch; v straight into vfirst (output 1)
  gemm_stage1_kernel<<<896, blk, 0, stream>>>(
      xrB, xkB, xvB, WrT, WkT, WvT, r_btc, k_btc, vfirst,
      xwB, xaB, xgB, w1T, a1T, g1T, hwB, haB, hgB);

  // LoRA stage 2 (w/a/g) in one launch
  lora2_kernel<<<dim3(32, 8, 3), blk, 0, stream>>>(
      hwB, haB, hgB, w2T, a2T, g2T, wraw, araw, gfB);

  // chunked-DPLR scan phase 1 (postproc fused, 2 blocks/CU)
  constexpr int CHUNK_LDS = 7 * 64 * RS * 2 + 64 * LBS * 2 + 64 * 4 + 4 * 64 * 4;
  hipFuncSetAttribute((const void*)chunk_ops_kernel,
                      hipFuncAttributeMaxDynamicSharedMemorySize, CHUNK_LDS);
  chunk_ops_kernel<<<1024, blk, CHUNK_LDS, stream>>>(
      r_btc, k_btc, vfirst, wraw, araw, w0, a0, k_k, k_a, r_k,
      McG, NcG, PcG, OlG, DkG, s3G);

  chunk_scan_kernel<<<64, blk, 0, stream>>>(McG, NcG, Sch);

  chunk_outgn_kernel<<<1024, blk, 0, stream>>>(PcG, OlG, Sch, s3G, vfirst, gfB,
                                               ln_g, ln_b, ygB);

  gemm_out_kernel<<<dim3(32, 8), blk, 0, stream>>>(ygB, WoT, outp);
}